// Round 8
// baseline (462.564 us; speedup 1.0000x reference)
//
#include <hip/hip_runtime.h>

// Problem constants: B=1024, L=64, N=65536, V=100000, E=300, RH=M=50, NC=3
// tree: balanced binary, parent=(i-1)//2, depths 0..6, locs 0..31 have children

typedef __attribute__((ext_vector_type(8))) short bf16x8;
typedef __attribute__((ext_vector_type(4))) float f32x4;

// ---- activations ----
__device__ __forceinline__ float fsig2(float x) {
    float e = __builtin_amdgcn_exp2f(-1.4426950408889634f * x);
    return __builtin_amdgcn_rcpf(1.0f + e);
}
__device__ __forceinline__ float ftanh2(float x) {
    float e = __builtin_amdgcn_exp2f(2.8853900817779268f * x);
    return 1.0f - 2.0f * __builtin_amdgcn_rcpf(1.0f + e);
}

// round-to-nearest-even f32 -> bf16 (returns upper 16 bits)
__device__ __forceinline__ unsigned short rne_bf16(float f) {
    unsigned u = __builtin_bit_cast(unsigned, f);
    unsigned r = u + 0x7fffu + ((u >> 16) & 1u);
    return (unsigned short)(r >> 16);
}
// fp32 -> bf16 hi + bf16 lo (RNE both limbs; combined residual ~2^-17 rel, unbiased)
__device__ __forceinline__ void split2(float f, unsigned short& h, unsigned short& l) {
    h = rne_bf16(f);
    float fh = __builtin_bit_cast(float, ((unsigned)h) << 16);
    float r = f - fh;   // exact (Sterbenz)
    l = rne_bf16(r);
}

__device__ __forceinline__ void async_lds16(const void* g, void* l) {
    __builtin_amdgcn_global_load_lds(
        (const __attribute__((address_space(1))) unsigned int*)g,
        (__attribute__((address_space(3))) unsigned int*)l, 16, 0, 0);
}

__device__ __forceinline__ bf16x8 pack8(const unsigned short* h) {
    bf16x8 v;
    #pragma unroll
    for (int e = 0; e < 8; ++e) v[e] = (short)h[e];
    return v;
}

// ---------------------------------------------------------------------------
// K0 (fused): convert weights [B1;B2] (rows = output cols, K contraction) to
// chunked hi|lo bf16 layout: out[(((c*2+h)*4 + kq)*BN + n)*8 + e] covers
// k = c*32 + kq*8 + e.  n >= Rreal or k >= K zero-filled.
// ---------------------------------------------------------------------------
__device__ __forceinline__ void conv_item(int q, const float* __restrict__ B1,
                                          const float* __restrict__ B2,
                                          int split, int K, int Rreal, int BN,
                                          unsigned short* __restrict__ out) {
    int n  = q % BN;
    int kq = (q / BN) & 3;
    int c  = q / (BN * 4);
    const float* row = (n < split) ? (B1 + (size_t)n * K) : (B2 + (size_t)(n - split) * K);
    unsigned short h[8], l[8];
    #pragma unroll
    for (int e = 0; e < 8; ++e) {
        int k = c * 32 + kq * 8 + e;
        float v = (n < Rreal && k < K) ? row[k] : 0.0f;
        split2(v, h[e], l[e]);
    }
    size_t hb = ((((size_t)c * 2 + 0) * 4 + kq) * BN + n) * 8;
    size_t lb = ((((size_t)c * 2 + 1) * 4 + kq) * BN + n) * 8;
    *(ushort4*)&out[hb]     = make_ushort4(h[0], h[1], h[2], h[3]);
    *(ushort4*)&out[hb + 4] = make_ushort4(h[4], h[5], h[6], h[7]);
    *(ushort4*)&out[lb]     = make_ushort4(l[0], l[1], l[2], l[3]);
    *(ushort4*)&out[lb + 4] = make_ushort4(l[4], l[5], l[6], l[7]);
}

constexpr int WHC_DIR = 2 * 2 * 4 * 208 * 8;   // shorts per direction = 26624

__global__ void conv_fused(const float* __restrict__ Wihf, const float* __restrict__ Wihb,
                           const float* __restrict__ Wiou, const float* __restrict__ Hw,
                           const float* __restrict__ Whhf, const float* __restrict__ Whhb,
                           unsigned short* __restrict__ B1c,
                           unsigned short* __restrict__ B3c,
                           unsigned short* __restrict__ Whc) {
    int q = blockIdx.x * 256 + threadIdx.x;
    if (q < 17920) {
        conv_item(q, Wihf, Wihb, 200, 300, 400, 448, B1c);
    } else if (q < 22016) {
        conv_item(q - 17920, Wiou, Hw, 150, 100, 200, 256, B3c);
    } else if (q < 23680) {
        conv_item(q - 22016, Whhf, Whhf, 200, 50, 200, 208, Whc);
    } else if (q < 25344) {
        conv_item(q - 23680, Whhb, Whhb, 200, 50, 200, 208, Whc + WHC_DIR);
    }
}

// ---------------------------------------------------------------------------
// Split-bf16 MFMA GEMM (round-3 verified version). BM=64 rows, BN padded
// cols, 256 thr = 4 waves column-split. Conflict-free LDS: A [h][kq][64][8],
// B [h][kq][BN][8] (pre-converted, async-staged). 3 mfma terms.
// ---------------------------------------------------------------------------
template<int BN, int KCH, int KREAL, int NCOLS, bool GATHER>
__global__ __launch_bounds__(256)
void gemm_split(const float* __restrict__ A, const int* __restrict__ ids,
                const unsigned short* __restrict__ Bc,
                const float* __restrict__ bias1, const float* __restrict__ bias2,
                int split, float* __restrict__ C) {
    constexpr int NTW = BN / 64;   // 16-col tiles per wave
    __shared__ __align__(16) unsigned short As[2 * 4 * 64 * 8];  // 8 KB
    __shared__ __align__(16) unsigned short Bt[64 * BN];

    const int tid = threadIdx.x;
    const int m0 = blockIdx.x * 64;
    const int w = tid >> 6, lane = tid & 63;
    const int r16 = lane & 15, quad = lane >> 4;
    const int wn = w * (BN / 4);

    const int mA = tid & 63, kqA = tid >> 6;
    const float* arow = GATHER ? (A + (size_t)ids[m0 + mA] * KREAL)
                               : (A + (size_t)(m0 + mA) * KREAL);

    float ar[8];
    {
        int k0 = kqA * 8;
        if (k0 + 8 <= KREAL) {
            float4 p = *(const float4*)(arow + k0);
            float4 q = *(const float4*)(arow + k0 + 4);
            ar[0]=p.x; ar[1]=p.y; ar[2]=p.z; ar[3]=p.w;
            ar[4]=q.x; ar[5]=q.y; ar[6]=q.z; ar[7]=q.w;
        } else {
            #pragma unroll
            for (int e = 0; e < 8; ++e) ar[e] = (k0 + e < KREAL) ? arow[k0 + e] : 0.0f;
        }
    }

    f32x4 acc[4][NTW] = {};

    for (int c = 0; c < KCH; ++c) {
        __syncthreads();
        {
            const unsigned short* src = Bc + (size_t)c * 64 * BN + tid * 8;
            #pragma unroll
            for (int i = 0; i < BN / 32; ++i)
                async_lds16(src + (size_t)i * 2048, Bt + i * 2048 + tid * 8);
        }
        {
            unsigned short h[8], l[8];
            #pragma unroll
            for (int e = 0; e < 8; ++e) split2(ar[e], h[e], l[e]);
            *(bf16x8*)&As[((0 * 4 + kqA) * 64 + mA) * 8] = pack8(h);
            *(bf16x8*)&As[((1 * 4 + kqA) * 64 + mA) * 8] = pack8(l);
        }
        __syncthreads();
        if (c + 1 < KCH) {
            int k0 = (c + 1) * 32 + kqA * 8;
            if (k0 + 8 <= KREAL) {
                float4 p = *(const float4*)(arow + k0);
                float4 q = *(const float4*)(arow + k0 + 4);
                ar[0]=p.x; ar[1]=p.y; ar[2]=p.z; ar[3]=p.w;
                ar[4]=q.x; ar[5]=q.y; ar[6]=q.z; ar[7]=q.w;
            } else {
                #pragma unroll
                for (int e = 0; e < 8; ++e) ar[e] = (k0 + e < KREAL) ? arow[k0 + e] : 0.0f;
            }
        }
        bf16x8 af[2][4];
        #pragma unroll
        for (int i = 0; i < 4; ++i) {
            af[0][i] = *(const bf16x8*)&As[((0 * 4 + quad) * 64 + i * 16 + r16) * 8];
            af[1][i] = *(const bf16x8*)&As[((1 * 4 + quad) * 64 + i * 16 + r16) * 8];
        }
        #pragma unroll
        for (int t = 0; t < NTW; ++t) {
            bf16x8 bh = *(const bf16x8*)&Bt[((0 * 4 + quad) * BN + wn + t * 16 + r16) * 8];
            bf16x8 bl = *(const bf16x8*)&Bt[((1 * 4 + quad) * BN + wn + t * 16 + r16) * 8];
            #pragma unroll
            for (int i = 0; i < 4; ++i) {
                acc[i][t] = __builtin_amdgcn_mfma_f32_16x16x32_bf16(af[0][i], bh, acc[i][t], 0, 0, 0);
                acc[i][t] = __builtin_amdgcn_mfma_f32_16x16x32_bf16(af[1][i], bh, acc[i][t], 0, 0, 0);
                acc[i][t] = __builtin_amdgcn_mfma_f32_16x16x32_bf16(af[0][i], bl, acc[i][t], 0, 0, 0);
            }
        }
    }

    #pragma unroll
    for (int t = 0; t < NTW; ++t) {
        int ncol = wn + t * 16 + r16;
        if (ncol < NCOLS) {
            float bv = (ncol < split) ? bias1[ncol] : bias2[ncol - split];
            #pragma unroll
            for (int i = 0; i < 4; ++i)
                #pragma unroll
                for (int r = 0; r < 4; ++r) {
                    int mrow = m0 + i * 16 + quad * 4 + r;
                    C[(size_t)mrow * NCOLS + ncol] = acc[i][t][r] + bv;
                }
        }
    }
}

// ---------------------------------------------------------------------------
// K2: MFMA-batched BiLSTM, 8 sentences/block, 256 blocks (round-7 verified).
// Counted-vmcnt sync: per step each wave issues exactly 2 DMA + 2 store
// instrs in pinned order; vmcnt(8) at barrier #1 waits exactly for L_t.
// ---------------------------------------------------------------------------
__global__ __launch_bounds__(256)
void lstm_mfma(const float* __restrict__ xg, const unsigned short* __restrict__ Whc,
               float* __restrict__ x) {
    const int bi = blockIdx.x;
    const int dir = bi & 1;
    const int b0 = (bi >> 1) * 8;
    const int tid = threadIdx.x;
    const int w = tid >> 6, lane = tid & 63;
    const int r16 = lane & 15, quad = lane >> 4;

    __shared__ __align__(16) unsigned short Ah[8 * 16 * 8];  // [kq][row16][8]
    __shared__ __align__(16) unsigned short Al[8 * 16 * 8];
    __shared__ __align__(16) float G[208 * 20];              // [gate][row pad20]
    __shared__ __align__(16) float Xs[3][8][268];            // xg ring (lead 2)

    const int n0 = (w == 0) ? 0 : (w == 1) ? 4 : (w == 2) ? 7 : 10;
    const int nc = (w == 0) ? 4 : 3;

    const unsigned short* Wd = Whc + (size_t)dir * WHC_DIR;
    bf16x8 bfr[4][2][2];   // [tile][chunk][hi/lo]
    #pragma unroll
    for (int t = 0; t < 4; ++t) {
        int col = (n0 + ((t < nc) ? t : 0)) * 16 + r16;
        #pragma unroll
        for (int c = 0; c < 2; ++c)
            #pragma unroll
            for (int h = 0; h < 2; ++h)
                bfr[t][c][h] = *(const bf16x8*)&Wd[((((size_t)c * 2 + h) * 4 + quad) * 208 + col) * 8];
    }

    for (int q = tid; q < 512; q += 256) {
        ((unsigned*)Ah)[q] = 0u;   // rows 8..15 stay zero forever
        ((unsigned*)Al)[q] = 0u;
    }

    int ss[2], ms[2];
    bool act[2];
    #pragma unroll
    for (int j = 0; j < 2; ++j) {
        int q = w * 100 + lane + 64 * j;
        ss[j] = q & 7;
        ms[j] = q >> 3;
        act[j] = (lane + 64 * j) < 100;
    }
    float c_reg[2] = {0.0f, 0.0f};

    #pragma unroll
    for (int p = 0; p < 2; ++p) {
        int idx0 = dir ? (63 - p) : p;
        #pragma unroll
        for (int i = 0; i < 2; ++i) {
            int s = w * 2 + i;
            const float* src = xg + ((size_t)(b0 + s) * 64 + idx0) * 400 + dir * 200 + lane * 4;
            async_lds16(src, &Xs[p][s][lane * 4]);
        }
    }
    __syncthreads();

    for (int step = 0; step < 64; ++step) {
        const int buf = step % 3;
        const int idx = dir ? (63 - step) : step;
        {
            int stepn = step + 2; if (stepn > 63) stepn = 63;
            const int slot = (step + 2) % 3;
            const int idxn = dir ? (63 - stepn) : stepn;
            #pragma unroll
            for (int i = 0; i < 2; ++i) {
                int s = w * 2 + i;
                const float* src = xg + ((size_t)(b0 + s) * 64 + idxn) * 400 + dir * 200 + lane * 4;
                async_lds16(src, &Xs[slot][s][lane * 4]);
            }
            __builtin_amdgcn_sched_barrier(0);
        }
        bf16x8 ah[2], al[2];
        #pragma unroll
        for (int c = 0; c < 2; ++c) {
            ah[c] = *(const bf16x8*)&Ah[((c * 4 + quad) * 16 + r16) * 8];
            al[c] = *(const bf16x8*)&Al[((c * 4 + quad) * 16 + r16) * 8];
        }
        f32x4 acc[4] = {};
        #pragma unroll
        for (int t = 0; t < 4; ++t) {
            if (t < nc) {
                #pragma unroll
                for (int c = 0; c < 2; ++c) {
                    acc[t] = __builtin_amdgcn_mfma_f32_16x16x32_bf16(ah[c], bfr[t][c][0], acc[t], 0, 0, 0);
                    acc[t] = __builtin_amdgcn_mfma_f32_16x16x32_bf16(al[c], bfr[t][c][0], acc[t], 0, 0, 0);
                    acc[t] = __builtin_amdgcn_mfma_f32_16x16x32_bf16(ah[c], bfr[t][c][1], acc[t], 0, 0, 0);
                }
            }
        }
        #pragma unroll
        for (int t = 0; t < 4; ++t) {
            if (t < nc) {
                int col = (n0 + t) * 16 + r16;
                *(f32x4*)&G[col * 20 + quad * 4] = acc[t];
            }
        }
        asm volatile("s_waitcnt lgkmcnt(0) vmcnt(8)" ::: "memory");
        __builtin_amdgcn_sched_barrier(0);
        __builtin_amdgcn_s_barrier();
        __builtin_amdgcn_sched_barrier(0);
        #pragma unroll
        for (int j = 0; j < 2; ++j) {
            if (act[j]) {
                int s = ss[j], m = ms[j];
                float gi = G[m * 20 + s]         + Xs[buf][s][m];
                float gf = G[(m + 50) * 20 + s]  + Xs[buf][s][m + 50];
                float gg = G[(m + 100) * 20 + s] + Xs[buf][s][m + 100];
                float go = G[(m + 150) * 20 + s] + Xs[buf][s][m + 150];
                c_reg[j] = fsig2(gf) * c_reg[j] + fsig2(gi) * ftanh2(gg);
                float h = fsig2(go) * ftanh2(c_reg[j]);
                unsigned short hh, hl;
                split2(h, hh, hl);
                Ah[(m >> 3) * 128 + s * 8 + (m & 7)] = hh;
                Al[(m >> 3) * 128 + s * 8 + (m & 7)] = hl;
                x[((size_t)(b0 + s) * 64 + idx) * 100 + dir * 50 + m] = h;
            }
        }
        asm volatile("s_waitcnt lgkmcnt(0)" ::: "memory");
        __builtin_amdgcn_sched_barrier(0);
        __builtin_amdgcn_s_barrier();
        __builtin_amdgcn_sched_barrier(0);
    }
}

// ---------------------------------------------------------------------------
// K4: ChildSum TreeLSTM + masked pool + classifier. One block = one sentence.
// Round-8 rewrite (counters: MfmaUtil 0, VALU 36%, HBM 4%, Occ 20%, VGPR
// 120): drop the per-thread ur/fr register rows (they cost ~100 VGPR ->
// 2 waves/SIMD); read Uw/Fw rows from global per item (30KB+10KB, L1/L2-
// resident, shared by all blocks) and PARALLELIZE the msg phase over
// (a,col) and the f phase over (a,m) across all 256 threads with 4-way
// split accumulators (short dep chains).  tmask staged in LDS; pool is a
// two-stage parallel reduction.  exp2-based activations (validated in K2).
// ---------------------------------------------------------------------------
__global__ __launch_bounds__(256)
void tree_kernel(const float* __restrict__ C2,
                 const float* __restrict__ Uw, const float* __restrict__ Ub,
                 const float* __restrict__ Fw, const float* __restrict__ Fb,
                 const float* __restrict__ tmask,
                 const float* __restrict__ Cw, const float* __restrict__ Cb,
                 float* __restrict__ out) {
    const int b = blockIdx.x;
    const int tid = threadIdx.x;

    __shared__ __align__(16) float h_sum[32][52];
    __shared__ __align__(16) float fc_sum[32][52];
    __shared__ __align__(16) float hcur[32][52];
    __shared__ __align__(16) float mcur[32][52];
    __shared__ float msg[16][152];
    __shared__ float hfin[64][50];
    __shared__ float pool[52];
    __shared__ float tms[64];
    __shared__ float red[4][52];

    for (int q = tid; q < 32 * 52; q += 256) {
        h_sum[q / 52][q % 52] = 0.0f;
        fc_sum[q / 52][q % 52] = 0.0f;
    }
    if (tid < 64) tms[tid] = tmask[(size_t)b * 64 + tid];
    __syncthreads();

    const float* c2b = C2 + (size_t)b * 64 * 200;

    for (int lvl = 6; lvl >= 0; --lvl) {
        const int lo = (1 << lvl) - 1;
        const int hi = min((1 << (lvl + 1)) - 2, 63);
        const int A = hi - lo + 1;
        const int chn = max(0, min(hi, 31) - lo + 1);

        // ---- msg = Ub + Uiou @ h_sum, parallel over (a, col) ----
        for (int q = tid; q < chn * 150; q += 256) {
            int a = q / 150, col = q - a * 150;
            const float* urow = Uw + col * 50;
            const float* hs = &h_sum[lo + a][0];
            float a0 = 0.0f, a1 = 0.0f, a2 = 0.0f, a3 = 0.0f;
            #pragma unroll
            for (int k4 = 0; k4 < 12; ++k4) {
                float4 u4 = *(const float4*)&urow[k4 * 4];
                float4 h4 = *(const float4*)&hs[k4 * 4];
                a0 += u4.x * h4.x; a1 += u4.y * h4.y;
                a2 += u4.z * h4.z; a3 += u4.w * h4.w;
            }
            msg[a][col] = Ub[col] + (a0 + a1) + (a2 + a3)
                        + urow[48] * hs[48] + urow[49] * hs[49];
        }
        __syncthreads();

        // ---- gates, parallel over (a, m) ----
        for (int q = tid; q < A * 50; q += 256) {
            int a = q / 50, m = q - a * 50;
            int loc = lo + a;
            const float* base = c2b + (size_t)loc * 200;
            bool ch = (a < chn);
            float ig = base[m]       + (ch ? msg[a][m]       : 0.0f);
            float og = base[50 + m]  + (ch ? msg[a][50 + m]  : 0.0f);
            float ug = base[100 + m] + (ch ? msg[a][100 + m] : 0.0f);
            float cn = fsig2(ig) * ftanh2(ug) + (ch ? fc_sum[loc][m] : 0.0f);
            float hn = base[150 + m] + fsig2(og) * ftanh2(cn);
            hcur[a][m] = hn;
            mcur[a][m] = cn;
            hfin[loc][m] = hn;
        }
        __syncthreads();

        // ---- f-gate: mcur *= sigmoid(Fb + Fw @ hcur), parallel over (a, m) ----
        for (int q = tid; q < A * 50; q += 256) {
            int a = q / 50, m = q - a * 50;
            const float* frow = Fw + m * 50;
            const float* hc = &hcur[a][0];
            float a0 = 0.0f, a1 = 0.0f, a2 = 0.0f, a3 = 0.0f;
            #pragma unroll
            for (int k4 = 0; k4 < 12; ++k4) {
                float4 f4 = *(const float4*)&frow[k4 * 4];
                float4 h4 = *(const float4*)&hc[k4 * 4];
                a0 += f4.x * h4.x; a1 += f4.y * h4.y;
                a2 += f4.z * h4.z; a3 += f4.w * h4.w;
            }
            float acc = Fb[m] + (a0 + a1) + (a2 + a3)
                      + frow[48] * hc[48] + frow[49] * hc[49];
            mcur[a][m] = fsig2(acc) * mcur[a][m];
        }
        __syncthreads();

        // ---- scatter to parents ----
        if (lvl > 0) {
            const int plo = (lo - 1) >> 1, phi = (hi - 1) >> 1;
            const int P = phi - plo + 1;
            for (int q = tid; q < P * 50; q += 256) {
                int pi = q / 50, m = q - pi * 50;
                int p = plo + pi;
                int c1 = 2 * p + 1, c2i = 2 * p + 2;
                float hs = hcur[c1 - lo][m];
                float fs = mcur[c1 - lo][m];
                if (c2i <= hi) { hs += hcur[c2i - lo][m]; fs += mcur[c2i - lo][m]; }
                h_sum[p][m] += hs;
                fc_sum[p][m] += fs;
            }
        }
        __syncthreads();
    }

    // ---- masked mean pool (two-stage parallel reduce) ----
    if (tid < 200) {
        int g = tid / 50, m = tid - g * 50;
        float part = 0.0f;
        for (int l = g; l < 64; l += 4) part += tms[l] * hfin[l][m];
        red[g][m] = part;
    }
    __syncthreads();
    if (tid < 50) {
        float ws = 0.0f;
        #pragma unroll
        for (int l = 0; l < 64; ++l) ws += tms[l];
        float acc = red[0][tid] + red[1][tid] + red[2][tid] + red[3][tid];
        float p = acc / ws;
        pool[tid] = p;
        out[3072 + (size_t)b * 50 + tid] = p;
    }
    __syncthreads();
    if (tid < 3) {
        float acc = Cb[tid];
        #pragma unroll
        for (int m = 0; m < 50; ++m) acc += Cw[tid * 50 + m] * pool[m];
        out[(size_t)b * 3 + tid] = acc;
    }
}

// ---------------------------------------------------------------------------
extern "C" void kernel_launch(void* const* d_in, const int* in_sizes, int n_in,
                              void* d_out, int out_size, void* d_ws, size_t ws_size,
                              hipStream_t stream) {
    (void)in_sizes; (void)n_in; (void)out_size; (void)ws_size;
    const int*   ids   = (const int*)d_in[0];
    const float* tmask = (const float*)d_in[3];
    const float* table = (const float*)d_in[5];
    const float* Wihf  = (const float*)d_in[6];
    const float* Whhf  = (const float*)d_in[7];
    const float* bf    = (const float*)d_in[8];
    const float* Wihb  = (const float*)d_in[9];
    const float* Whhb  = (const float*)d_in[10];
    const float* bb    = (const float*)d_in[11];
    const float* Wiou  = (const float*)d_in[12];
    const float* Uiouw = (const float*)d_in[13];
    const float* Uioub = (const float*)d_in[14];
    const float* biou  = (const float*)d_in[15];
    const float* Ufw   = (const float*)d_in[16];
    const float* Ufb   = (const float*)d_in[17];
    const float* Hw    = (const float*)d_in[18];
    const float* Hb    = (const float*)d_in[19];
    const float* Cw    = (const float*)d_in[20];
    const float* Cb    = (const float*)d_in[21];
    float* out = (float*)d_out;

    float* wsf = (float*)d_ws;
    float* xg = wsf;                                  // 65536*400 f32 (C2 later)
    float* x  = wsf + (size_t)65536 * 400;            // 65536*100 f32
    float* C2 = wsf;
    unsigned short* B1c = (unsigned short*)(wsf + 32768000);  // 10*2*4*448*8 ush
    unsigned short* B3c = (unsigned short*)(wsf + 32911360);  // 4*2*4*256*8 ush
    unsigned short* Whc = (unsigned short*)(wsf + 32944128);  // 2 * WHC_DIR ush

    // K0: all weight pre-conversions in ONE launch (25344 items)
    conv_fused<<<99, 256, 0, stream>>>(Wihf, Wihb, Wiou, Hw, Whhf, Whhb,
                                       B1c, B3c, Whc);
    // K1: xg = gather(embed)@[W_ih_f;W_ih_b]^T + bias   (N x 400)
    gemm_split<448, 10, 300, 400, true><<<1024, 256, 0, stream>>>(
        table, ids, B1c, bf, bb, 200, xg);
    // K2: MFMA BiLSTM -> x (N x 100) = [hf | hb]   (8 sents/block, 256 blocks)
    lstm_mfma<<<256, 256, 0, stream>>>(xg, Whc, x);
    // K3: C2 = x@[W_iou^T | H_w^T] + [b_iou | H_b]   (N x 200)
    gemm_split<256, 4, 100, 200, false><<<1024, 256, 0, stream>>>(
        x, nullptr, B3c, biou, Hb, 150, C2);
    // K4: TreeLSTM + pool + classifier
    tree_kernel<<<1024, 256, 0, stream>>>(
        C2, Uiouw, Uioub, Ufw, Ufb, tmask, Cw, Cb, out);
}

// Round 9
// 437.609 us; speedup vs baseline: 1.0570x; 1.0570x over previous
//
#include <hip/hip_runtime.h>

// Problem constants: B=1024, L=64, N=65536, V=100000, E=300, RH=M=50, NC=3
// tree: balanced binary, parent=(i-1)//2, depths 0..6, locs 0..31 have children

typedef __attribute__((ext_vector_type(8))) short bf16x8;
typedef __attribute__((ext_vector_type(4))) float f32x4;

// ---- activations ----
__device__ __forceinline__ float fsig2(float x) {
    float e = __builtin_amdgcn_exp2f(-1.4426950408889634f * x);
    return __builtin_amdgcn_rcpf(1.0f + e);
}
__device__ __forceinline__ float ftanh2(float x) {
    float e = __builtin_amdgcn_exp2f(2.8853900817779268f * x);
    return 1.0f - 2.0f * __builtin_amdgcn_rcpf(1.0f + e);
}

// round-to-nearest-even f32 -> bf16 (returns upper 16 bits)
__device__ __forceinline__ unsigned short rne_bf16(float f) {
    unsigned u = __builtin_bit_cast(unsigned, f);
    unsigned r = u + 0x7fffu + ((u >> 16) & 1u);
    return (unsigned short)(r >> 16);
}
// fp32 -> bf16 hi + bf16 lo (RNE both limbs; combined residual ~2^-17 rel, unbiased)
__device__ __forceinline__ void split2(float f, unsigned short& h, unsigned short& l) {
    h = rne_bf16(f);
    float fh = __builtin_bit_cast(float, ((unsigned)h) << 16);
    float r = f - fh;   // exact (Sterbenz)
    l = rne_bf16(r);
}

__device__ __forceinline__ void async_lds16(const void* g, void* l) {
    __builtin_amdgcn_global_load_lds(
        (const __attribute__((address_space(1))) unsigned int*)g,
        (__attribute__((address_space(3))) unsigned int*)l, 16, 0, 0);
}

__device__ __forceinline__ bf16x8 pack8(const unsigned short* h) {
    bf16x8 v;
    #pragma unroll
    for (int e = 0; e < 8; ++e) v[e] = (short)h[e];
    return v;
}

// ---------------------------------------------------------------------------
// K0 (fused): convert weights [B1;B2] (rows = output cols, K contraction) to
// chunked hi|lo bf16 layout: out[(((c*2+h)*4 + kq)*BN + n)*8 + e] covers
// k = c*32 + kq*8 + e.  n >= Rreal or k >= K zero-filled.
// ---------------------------------------------------------------------------
__device__ __forceinline__ void conv_item(int q, const float* __restrict__ B1,
                                          const float* __restrict__ B2,
                                          int split, int K, int Rreal, int BN,
                                          unsigned short* __restrict__ out) {
    int n  = q % BN;
    int kq = (q / BN) & 3;
    int c  = q / (BN * 4);
    const float* row = (n < split) ? (B1 + (size_t)n * K) : (B2 + (size_t)(n - split) * K);
    unsigned short h[8], l[8];
    #pragma unroll
    for (int e = 0; e < 8; ++e) {
        int k = c * 32 + kq * 8 + e;
        float v = (n < Rreal && k < K) ? row[k] : 0.0f;
        split2(v, h[e], l[e]);
    }
    size_t hb = ((((size_t)c * 2 + 0) * 4 + kq) * BN + n) * 8;
    size_t lb = ((((size_t)c * 2 + 1) * 4 + kq) * BN + n) * 8;
    *(ushort4*)&out[hb]     = make_ushort4(h[0], h[1], h[2], h[3]);
    *(ushort4*)&out[hb + 4] = make_ushort4(h[4], h[5], h[6], h[7]);
    *(ushort4*)&out[lb]     = make_ushort4(l[0], l[1], l[2], l[3]);
    *(ushort4*)&out[lb + 4] = make_ushort4(l[4], l[5], l[6], l[7]);
}

constexpr int WHC_DIR = 2 * 2 * 4 * 208 * 8;   // shorts per direction = 26624

__global__ void conv_fused(const float* __restrict__ Wihf, const float* __restrict__ Wihb,
                           const float* __restrict__ Wiou, const float* __restrict__ Hw,
                           const float* __restrict__ Whhf, const float* __restrict__ Whhb,
                           unsigned short* __restrict__ B1c,
                           unsigned short* __restrict__ B3c,
                           unsigned short* __restrict__ Whc) {
    int q = blockIdx.x * 256 + threadIdx.x;
    if (q < 17920) {
        conv_item(q, Wihf, Wihb, 200, 300, 400, 448, B1c);
    } else if (q < 22016) {
        conv_item(q - 17920, Wiou, Hw, 150, 100, 200, 256, B3c);
    } else if (q < 23680) {
        conv_item(q - 22016, Whhf, Whhf, 200, 50, 200, 208, Whc);
    } else if (q < 25344) {
        conv_item(q - 23680, Whhb, Whhb, 200, 50, 200, 208, Whc + WHC_DIR);
    }
}

// ---------------------------------------------------------------------------
// Split-bf16 MFMA GEMM (round-3 verified version). BM=64 rows, BN padded
// cols, 256 thr = 4 waves column-split. Conflict-free LDS: A [h][kq][64][8],
// B [h][kq][BN][8] (pre-converted, async-staged). 3 mfma terms.
// ---------------------------------------------------------------------------
template<int BN, int KCH, int KREAL, int NCOLS, bool GATHER>
__global__ __launch_bounds__(256)
void gemm_split(const float* __restrict__ A, const int* __restrict__ ids,
                const unsigned short* __restrict__ Bc,
                const float* __restrict__ bias1, const float* __restrict__ bias2,
                int split, float* __restrict__ C) {
    constexpr int NTW = BN / 64;   // 16-col tiles per wave
    __shared__ __align__(16) unsigned short As[2 * 4 * 64 * 8];  // 8 KB
    __shared__ __align__(16) unsigned short Bt[64 * BN];

    const int tid = threadIdx.x;
    const int m0 = blockIdx.x * 64;
    const int w = tid >> 6, lane = tid & 63;
    const int r16 = lane & 15, quad = lane >> 4;
    const int wn = w * (BN / 4);

    const int mA = tid & 63, kqA = tid >> 6;
    const float* arow = GATHER ? (A + (size_t)ids[m0 + mA] * KREAL)
                               : (A + (size_t)(m0 + mA) * KREAL);

    float ar[8];
    {
        int k0 = kqA * 8;
        if (k0 + 8 <= KREAL) {
            float4 p = *(const float4*)(arow + k0);
            float4 q = *(const float4*)(arow + k0 + 4);
            ar[0]=p.x; ar[1]=p.y; ar[2]=p.z; ar[3]=p.w;
            ar[4]=q.x; ar[5]=q.y; ar[6]=q.z; ar[7]=q.w;
        } else {
            #pragma unroll
            for (int e = 0; e < 8; ++e) ar[e] = (k0 + e < KREAL) ? arow[k0 + e] : 0.0f;
        }
    }

    f32x4 acc[4][NTW] = {};

    for (int c = 0; c < KCH; ++c) {
        __syncthreads();
        {
            const unsigned short* src = Bc + (size_t)c * 64 * BN + tid * 8;
            #pragma unroll
            for (int i = 0; i < BN / 32; ++i)
                async_lds16(src + (size_t)i * 2048, Bt + i * 2048 + tid * 8);
        }
        {
            unsigned short h[8], l[8];
            #pragma unroll
            for (int e = 0; e < 8; ++e) split2(ar[e], h[e], l[e]);
            *(bf16x8*)&As[((0 * 4 + kqA) * 64 + mA) * 8] = pack8(h);
            *(bf16x8*)&As[((1 * 4 + kqA) * 64 + mA) * 8] = pack8(l);
        }
        __syncthreads();
        if (c + 1 < KCH) {
            int k0 = (c + 1) * 32 + kqA * 8;
            if (k0 + 8 <= KREAL) {
                float4 p = *(const float4*)(arow + k0);
                float4 q = *(const float4*)(arow + k0 + 4);
                ar[0]=p.x; ar[1]=p.y; ar[2]=p.z; ar[3]=p.w;
                ar[4]=q.x; ar[5]=q.y; ar[6]=q.z; ar[7]=q.w;
            } else {
                #pragma unroll
                for (int e = 0; e < 8; ++e) ar[e] = (k0 + e < KREAL) ? arow[k0 + e] : 0.0f;
            }
        }
        bf16x8 af[2][4];
        #pragma unroll
        for (int i = 0; i < 4; ++i) {
            af[0][i] = *(const bf16x8*)&As[((0 * 4 + quad) * 64 + i * 16 + r16) * 8];
            af[1][i] = *(const bf16x8*)&As[((1 * 4 + quad) * 64 + i * 16 + r16) * 8];
        }
        #pragma unroll
        for (int t = 0; t < NTW; ++t) {
            bf16x8 bh = *(const bf16x8*)&Bt[((0 * 4 + quad) * BN + wn + t * 16 + r16) * 8];
            bf16x8 bl = *(const bf16x8*)&Bt[((1 * 4 + quad) * BN + wn + t * 16 + r16) * 8];
            #pragma unroll
            for (int i = 0; i < 4; ++i) {
                acc[i][t] = __builtin_amdgcn_mfma_f32_16x16x32_bf16(af[0][i], bh, acc[i][t], 0, 0, 0);
                acc[i][t] = __builtin_amdgcn_mfma_f32_16x16x32_bf16(af[1][i], bh, acc[i][t], 0, 0, 0);
                acc[i][t] = __builtin_amdgcn_mfma_f32_16x16x32_bf16(af[0][i], bl, acc[i][t], 0, 0, 0);
            }
        }
    }

    #pragma unroll
    for (int t = 0; t < NTW; ++t) {
        int ncol = wn + t * 16 + r16;
        if (ncol < NCOLS) {
            float bv = (ncol < split) ? bias1[ncol] : bias2[ncol - split];
            #pragma unroll
            for (int i = 0; i < 4; ++i)
                #pragma unroll
                for (int r = 0; r < 4; ++r) {
                    int mrow = m0 + i * 16 + quad * 4 + r;
                    C[(size_t)mrow * NCOLS + ncol] = acc[i][t][r] + bv;
                }
        }
    }
}

// ---------------------------------------------------------------------------
// K2: MFMA-batched BiLSTM, 8 sentences/block, 256 blocks (round-7 verified).
// Counted-vmcnt sync: per step each wave issues exactly 2 DMA + 2 store
// instrs in pinned order; vmcnt(8) at barrier #1 waits exactly for L_t.
// ---------------------------------------------------------------------------
__global__ __launch_bounds__(256)
void lstm_mfma(const float* __restrict__ xg, const unsigned short* __restrict__ Whc,
               float* __restrict__ x) {
    const int bi = blockIdx.x;
    const int dir = bi & 1;
    const int b0 = (bi >> 1) * 8;
    const int tid = threadIdx.x;
    const int w = tid >> 6, lane = tid & 63;
    const int r16 = lane & 15, quad = lane >> 4;

    __shared__ __align__(16) unsigned short Ah[8 * 16 * 8];  // [kq][row16][8]
    __shared__ __align__(16) unsigned short Al[8 * 16 * 8];
    __shared__ __align__(16) float G[208 * 20];              // [gate][row pad20]
    __shared__ __align__(16) float Xs[3][8][268];            // xg ring (lead 2)

    const int n0 = (w == 0) ? 0 : (w == 1) ? 4 : (w == 2) ? 7 : 10;
    const int nc = (w == 0) ? 4 : 3;

    const unsigned short* Wd = Whc + (size_t)dir * WHC_DIR;
    bf16x8 bfr[4][2][2];   // [tile][chunk][hi/lo]
    #pragma unroll
    for (int t = 0; t < 4; ++t) {
        int col = (n0 + ((t < nc) ? t : 0)) * 16 + r16;
        #pragma unroll
        for (int c = 0; c < 2; ++c)
            #pragma unroll
            for (int h = 0; h < 2; ++h)
                bfr[t][c][h] = *(const bf16x8*)&Wd[((((size_t)c * 2 + h) * 4 + quad) * 208 + col) * 8];
    }

    for (int q = tid; q < 512; q += 256) {
        ((unsigned*)Ah)[q] = 0u;   // rows 8..15 stay zero forever
        ((unsigned*)Al)[q] = 0u;
    }

    int ss[2], ms[2];
    bool act[2];
    #pragma unroll
    for (int j = 0; j < 2; ++j) {
        int q = w * 100 + lane + 64 * j;
        ss[j] = q & 7;
        ms[j] = q >> 3;
        act[j] = (lane + 64 * j) < 100;
    }
    float c_reg[2] = {0.0f, 0.0f};

    #pragma unroll
    for (int p = 0; p < 2; ++p) {
        int idx0 = dir ? (63 - p) : p;
        #pragma unroll
        for (int i = 0; i < 2; ++i) {
            int s = w * 2 + i;
            const float* src = xg + ((size_t)(b0 + s) * 64 + idx0) * 400 + dir * 200 + lane * 4;
            async_lds16(src, &Xs[p][s][lane * 4]);
        }
    }
    __syncthreads();

    for (int step = 0; step < 64; ++step) {
        const int buf = step % 3;
        const int idx = dir ? (63 - step) : step;
        {
            int stepn = step + 2; if (stepn > 63) stepn = 63;
            const int slot = (step + 2) % 3;
            const int idxn = dir ? (63 - stepn) : stepn;
            #pragma unroll
            for (int i = 0; i < 2; ++i) {
                int s = w * 2 + i;
                const float* src = xg + ((size_t)(b0 + s) * 64 + idxn) * 400 + dir * 200 + lane * 4;
                async_lds16(src, &Xs[slot][s][lane * 4]);
            }
            __builtin_amdgcn_sched_barrier(0);
        }
        bf16x8 ah[2], al[2];
        #pragma unroll
        for (int c = 0; c < 2; ++c) {
            ah[c] = *(const bf16x8*)&Ah[((c * 4 + quad) * 16 + r16) * 8];
            al[c] = *(const bf16x8*)&Al[((c * 4 + quad) * 16 + r16) * 8];
        }
        f32x4 acc[4] = {};
        #pragma unroll
        for (int t = 0; t < 4; ++t) {
            if (t < nc) {
                #pragma unroll
                for (int c = 0; c < 2; ++c) {
                    acc[t] = __builtin_amdgcn_mfma_f32_16x16x32_bf16(ah[c], bfr[t][c][0], acc[t], 0, 0, 0);
                    acc[t] = __builtin_amdgcn_mfma_f32_16x16x32_bf16(al[c], bfr[t][c][0], acc[t], 0, 0, 0);
                    acc[t] = __builtin_amdgcn_mfma_f32_16x16x32_bf16(ah[c], bfr[t][c][1], acc[t], 0, 0, 0);
                }
            }
        }
        #pragma unroll
        for (int t = 0; t < 4; ++t) {
            if (t < nc) {
                int col = (n0 + t) * 16 + r16;
                *(f32x4*)&G[col * 20 + quad * 4] = acc[t];
            }
        }
        asm volatile("s_waitcnt lgkmcnt(0) vmcnt(8)" ::: "memory");
        __builtin_amdgcn_sched_barrier(0);
        __builtin_amdgcn_s_barrier();
        __builtin_amdgcn_sched_barrier(0);
        #pragma unroll
        for (int j = 0; j < 2; ++j) {
            if (act[j]) {
                int s = ss[j], m = ms[j];
                float gi = G[m * 20 + s]         + Xs[buf][s][m];
                float gf = G[(m + 50) * 20 + s]  + Xs[buf][s][m + 50];
                float gg = G[(m + 100) * 20 + s] + Xs[buf][s][m + 100];
                float go = G[(m + 150) * 20 + s] + Xs[buf][s][m + 150];
                c_reg[j] = fsig2(gf) * c_reg[j] + fsig2(gi) * ftanh2(gg);
                float h = fsig2(go) * ftanh2(c_reg[j]);
                unsigned short hh, hl;
                split2(h, hh, hl);
                Ah[(m >> 3) * 128 + s * 8 + (m & 7)] = hh;
                Al[(m >> 3) * 128 + s * 8 + (m & 7)] = hl;
                x[((size_t)(b0 + s) * 64 + idx) * 100 + dir * 50 + m] = h;
            }
        }
        asm volatile("s_waitcnt lgkmcnt(0)" ::: "memory");
        __builtin_amdgcn_sched_barrier(0);
        __builtin_amdgcn_s_barrier();
        __builtin_amdgcn_sched_barrier(0);
    }
}

// ---------------------------------------------------------------------------
// K4: ChildSum TreeLSTM + masked pool + classifier. One block = one sentence.
// Round-9: weights-in-LDS + parallel phases (the missing cell of the r7/r8
// matrix: r7 = regs+serial 84us, r8 = global+parallel 126us).
//   - U_iou_w staged in LDS [150][52] (stride 52 floats = 13-quad swizzle,
//     conflict-free ds_read_b128); read 3 rows per gate item.
//   - msg fused into gates (each msg element consumed exactly once -> zero
//     extra FLOPs, -1 barrier/level, msg buffer gone).
//   - scatter fused into f-phase via LDS atomicAdd (ds_add_f32) on
//     h_sum/fc_sum (-1 barrier/level, mcur is the only extra state).
//   - pool accumulated on the fly (tms[loc]*hn at gate time, LDS atomic,
//     skip when mask==0) -> hfin buffer gone, no final 64-iter serial loop.
//   - Fw read from global (L2) in the f-phase: 1/3 the weight traffic of
//     gates; LDS budget spent on the 3x-reused Uw.
// 2 barriers/level (14 total vs 29); ~57 KB LDS -> 2 blocks/CU.
// ---------------------------------------------------------------------------
__global__ __launch_bounds__(256)
void tree_kernel(const float* __restrict__ C2,
                 const float* __restrict__ Uw, const float* __restrict__ Ub,
                 const float* __restrict__ Fw, const float* __restrict__ Fb,
                 const float* __restrict__ tmask,
                 const float* __restrict__ Cw, const float* __restrict__ Cb,
                 float* __restrict__ out) {
    const int b = blockIdx.x;
    const int tid = threadIdx.x;

    __shared__ __align__(16) float Us[150][52];    // 31200 B, U_iou_w rows
    __shared__ __align__(16) float h_sum[32][52];
    __shared__ __align__(16) float fc_sum[32][52];
    __shared__ __align__(16) float hcur[32][52];
    __shared__ float mcur[32][50];
    __shared__ float pool[52];
    __shared__ float tms[64];

    for (int q = tid; q < 7500; q += 256) Us[q / 50][q % 50] = Uw[q];
    for (int q = tid; q < 32 * 52; q += 256) {
        h_sum[q / 52][q % 52] = 0.0f;
        fc_sum[q / 52][q % 52] = 0.0f;
    }
    if (tid < 64) tms[tid] = tmask[(size_t)b * 64 + tid];
    if (tid < 52) pool[tid] = 0.0f;
    __syncthreads();

    const float* c2b = C2 + (size_t)b * 64 * 200;

    for (int lvl = 6; lvl >= 0; --lvl) {
        const int lo = (1 << lvl) - 1;
        const int hi = min((1 << (lvl + 1)) - 2, 63);
        const int A = hi - lo + 1;
        const int chn = max(0, min(hi, 31) - lo + 1);

        // ---- G: gates with msg fused ----
        for (int q = tid; q < A * 50; q += 256) {
            int a = q / 50, m = q - a * 50;
            int loc = lo + a;
            const float* base = c2b + (size_t)loc * 200;
            bool ch = (a < chn);
            float mi = 0.0f, mo = 0.0f, mu = 0.0f, fcv = 0.0f;
            if (ch) {
                float4 H[12];
                #pragma unroll
                for (int j = 0; j < 12; ++j) H[j] = *(const float4*)&h_sum[loc][j * 4];
                float h48 = h_sum[loc][48], h49 = h_sum[loc][49];
                const float* u0 = &Us[m][0];
                const float* u1 = &Us[50 + m][0];
                const float* u2 = &Us[100 + m][0];
                float i0=0,i1=0,i2=0,i3=0, o0=0,o1=0,o2=0,o3=0, g0=0,g1=0,g2=0,g3=0;
                #pragma unroll
                for (int j = 0; j < 12; ++j) {
                    float4 a4 = *(const float4*)&u0[j * 4];
                    float4 b4 = *(const float4*)&u1[j * 4];
                    float4 c4 = *(const float4*)&u2[j * 4];
                    i0 += a4.x*H[j].x; i1 += a4.y*H[j].y; i2 += a4.z*H[j].z; i3 += a4.w*H[j].w;
                    o0 += b4.x*H[j].x; o1 += b4.y*H[j].y; o2 += b4.z*H[j].z; o3 += b4.w*H[j].w;
                    g0 += c4.x*H[j].x; g1 += c4.y*H[j].y; g2 += c4.z*H[j].z; g3 += c4.w*H[j].w;
                }
                mi = Ub[m]       + (i0 + i1) + (i2 + i3) + u0[48]*h48 + u0[49]*h49;
                mo = Ub[50 + m]  + (o0 + o1) + (o2 + o3) + u1[48]*h48 + u1[49]*h49;
                mu = Ub[100 + m] + (g0 + g1) + (g2 + g3) + u2[48]*h48 + u2[49]*h49;
                fcv = fc_sum[loc][m];
            }
            float ig = base[m] + mi;
            float og = base[50 + m] + mo;
            float ug = base[100 + m] + mu;
            float cn = fsig2(ig) * ftanh2(ug) + fcv;
            float hn = base[150 + m] + fsig2(og) * ftanh2(cn);
            hcur[a][m] = hn;
            mcur[a][m] = cn;
            float tv = tms[loc];
            if (tv != 0.0f) atomicAdd(&pool[m], tv * hn);
        }
        __syncthreads();

        // ---- F + scatter (skip at root) ----
        if (lvl > 0) {
            for (int q = tid; q < A * 50; q += 256) {
                int a = q / 50, m = q - a * 50;
                int loc = lo + a;
                const float* frow = Fw + m * 50;
                const float* hc = &hcur[a][0];
                float a0 = 0, a1 = 0, a2 = 0, a3 = 0;
                #pragma unroll
                for (int j = 0; j < 12; ++j) {
                    float4 f4 = *(const float4*)&frow[j * 4];
                    float4 h4 = *(const float4*)&hc[j * 4];
                    a0 += f4.x*h4.x; a1 += f4.y*h4.y; a2 += f4.z*h4.z; a3 += f4.w*h4.w;
                }
                float acc = Fb[m] + (a0 + a1) + (a2 + a3)
                          + frow[48]*hc[48] + frow[49]*hc[49];
                float fm = fsig2(acc) * mcur[a][m];
                int p = (loc - 1) >> 1;
                atomicAdd(&h_sum[p][m], hcur[a][m]);
                atomicAdd(&fc_sum[p][m], fm);
            }
        }
        __syncthreads();
    }

    if (tid < 50) {
        float ws = 0.0f;
        #pragma unroll
        for (int l = 0; l < 64; ++l) ws += tms[l];
        float p = pool[tid] / ws;
        pool[tid] = p;
        out[3072 + (size_t)b * 50 + tid] = p;
    }
    __syncthreads();
    if (tid < 3) {
        float acc = Cb[tid];
        #pragma unroll
        for (int m = 0; m < 50; ++m) acc += Cw[tid * 50 + m] * pool[m];
        out[(size_t)b * 3 + tid] = acc;
    }
}

// ---------------------------------------------------------------------------
extern "C" void kernel_launch(void* const* d_in, const int* in_sizes, int n_in,
                              void* d_out, int out_size, void* d_ws, size_t ws_size,
                              hipStream_t stream) {
    (void)in_sizes; (void)n_in; (void)out_size; (void)ws_size;
    const int*   ids   = (const int*)d_in[0];
    const float* tmask = (const float*)d_in[3];
    const float* table = (const float*)d_in[5];
    const float* Wihf  = (const float*)d_in[6];
    const float* Whhf  = (const float*)d_in[7];
    const float* bf    = (const float*)d_in[8];
    const float* Wihb  = (const float*)d_in[9];
    const float* Whhb  = (const float*)d_in[10];
    const float* bb    = (const float*)d_in[11];
    const float* Wiou  = (const float*)d_in[12];
    const float* Uiouw = (const float*)d_in[13];
    const float* Uioub = (const float*)d_in[14];
    const float* biou  = (const float*)d_in[15];
    const float* Ufw   = (const float*)d_in[16];
    const float* Ufb   = (const float*)d_in[17];
    const float* Hw    = (const float*)d_in[18];
    const float* Hb    = (const float*)d_in[19];
    const float* Cw    = (const float*)d_in[20];
    const float* Cb    = (const float*)d_in[21];
    float* out = (float*)d_out;

    float* wsf = (float*)d_ws;
    float* xg = wsf;                                  // 65536*400 f32 (C2 later)
    float* x  = wsf + (size_t)65536 * 400;            // 65536*100 f32
    float* C2 = wsf;
    unsigned short* B1c = (unsigned short*)(wsf + 32768000);  // 10*2*4*448*8 ush
    unsigned short* B3c = (unsigned short*)(wsf + 32911360);  // 4*2*4*256*8 ush
    unsigned short* Whc = (unsigned short*)(wsf + 32944128);  // 2 * WHC_DIR ush

    // K0: all weight pre-conversions in ONE launch (25344 items)
    conv_fused<<<99, 256, 0, stream>>>(Wihf, Wihb, Wiou, Hw, Whhf, Whhb,
                                       B1c, B3c, Whc);
    // K1: xg = gather(embed)@[W_ih_f;W_ih_b]^T + bias   (N x 400)
    gemm_split<448, 10, 300, 400, true><<<1024, 256, 0, stream>>>(
        table, ids, B1c, bf, bb, 200, xg);
    // K2: MFMA BiLSTM -> x (N x 100) = [hf | hb]   (8 sents/block, 256 blocks)
    lstm_mfma<<<256, 256, 0, stream>>>(xg, Whc, x);
    // K3: C2 = x@[W_iou^T | H_w^T] + [b_iou | H_b]   (N x 200)
    gemm_split<256, 4, 100, 200, false><<<1024, 256, 0, stream>>>(
        x, nullptr, B3c, biou, Hb, 150, C2);
    // K4: TreeLSTM + pool + classifier
    tree_kernel<<<1024, 256, 0, stream>>>(
        C2, Uiouw, Uioub, Ufw, Ufb, tmask, Cw, Cb, out);
}

// Round 10
// 418.623 us; speedup vs baseline: 1.1050x; 1.0454x over previous
//
#include <hip/hip_runtime.h>

// Problem constants: B=1024, L=64, N=65536, V=100000, E=300, RH=M=50, NC=3
// tree: balanced binary, parent=(i-1)//2, depths 0..6, locs 0..31 have children

typedef __attribute__((ext_vector_type(8))) short bf16x8;
typedef __attribute__((ext_vector_type(4))) float f32x4;

// ---- activations ----
__device__ __forceinline__ float fsig2(float x) {
    float e = __builtin_amdgcn_exp2f(-1.4426950408889634f * x);
    return __builtin_amdgcn_rcpf(1.0f + e);
}
__device__ __forceinline__ float ftanh2(float x) {
    float e = __builtin_amdgcn_exp2f(2.8853900817779268f * x);
    return 1.0f - 2.0f * __builtin_amdgcn_rcpf(1.0f + e);
}

// round-to-nearest-even f32 -> bf16 (returns upper 16 bits)
__device__ __forceinline__ unsigned short rne_bf16(float f) {
    unsigned u = __builtin_bit_cast(unsigned, f);
    unsigned r = u + 0x7fffu + ((u >> 16) & 1u);
    return (unsigned short)(r >> 16);
}
// fp32 -> bf16 hi + bf16 lo (RNE both limbs; combined residual ~2^-17 rel, unbiased)
__device__ __forceinline__ void split2(float f, unsigned short& h, unsigned short& l) {
    h = rne_bf16(f);
    float fh = __builtin_bit_cast(float, ((unsigned)h) << 16);
    float r = f - fh;   // exact (Sterbenz)
    l = rne_bf16(r);
}

__device__ __forceinline__ void async_lds16(const void* g, void* l) {
    __builtin_amdgcn_global_load_lds(
        (const __attribute__((address_space(1))) unsigned int*)g,
        (__attribute__((address_space(3))) unsigned int*)l, 16, 0, 0);
}

__device__ __forceinline__ bf16x8 pack8(const unsigned short* h) {
    bf16x8 v;
    #pragma unroll
    for (int e = 0; e < 8; ++e) v[e] = (short)h[e];
    return v;
}

// ---------------------------------------------------------------------------
// K0 (fused): convert weights [B1;B2] (rows = output cols, K contraction) to
// chunked hi|lo bf16 layout: out[(((c*2+h)*4 + kq)*BN + n)*8 + e] covers
// k = c*32 + kq*8 + e.  n >= Rreal or k >= K zero-filled.
// ---------------------------------------------------------------------------
__device__ __forceinline__ void conv_item(int q, const float* __restrict__ B1,
                                          const float* __restrict__ B2,
                                          int split, int K, int Rreal, int BN,
                                          unsigned short* __restrict__ out) {
    int n  = q % BN;
    int kq = (q / BN) & 3;
    int c  = q / (BN * 4);
    const float* row = (n < split) ? (B1 + (size_t)n * K) : (B2 + (size_t)(n - split) * K);
    unsigned short h[8], l[8];
    #pragma unroll
    for (int e = 0; e < 8; ++e) {
        int k = c * 32 + kq * 8 + e;
        float v = (n < Rreal && k < K) ? row[k] : 0.0f;
        split2(v, h[e], l[e]);
    }
    size_t hb = ((((size_t)c * 2 + 0) * 4 + kq) * BN + n) * 8;
    size_t lb = ((((size_t)c * 2 + 1) * 4 + kq) * BN + n) * 8;
    *(ushort4*)&out[hb]     = make_ushort4(h[0], h[1], h[2], h[3]);
    *(ushort4*)&out[hb + 4] = make_ushort4(h[4], h[5], h[6], h[7]);
    *(ushort4*)&out[lb]     = make_ushort4(l[0], l[1], l[2], l[3]);
    *(ushort4*)&out[lb + 4] = make_ushort4(l[4], l[5], l[6], l[7]);
}

constexpr int WHC_DIR = 2 * 2 * 4 * 208 * 8;   // shorts per direction = 26624

__global__ void conv_fused(const float* __restrict__ Wihf, const float* __restrict__ Wihb,
                           const float* __restrict__ Wiou, const float* __restrict__ Hw,
                           const float* __restrict__ Whhf, const float* __restrict__ Whhb,
                           unsigned short* __restrict__ B1c,
                           unsigned short* __restrict__ B3c,
                           unsigned short* __restrict__ Whc) {
    int q = blockIdx.x * 256 + threadIdx.x;
    if (q < 17920) {
        conv_item(q, Wihf, Wihb, 200, 300, 400, 448, B1c);
    } else if (q < 22016) {
        conv_item(q - 17920, Wiou, Hw, 150, 100, 200, 256, B3c);
    } else if (q < 23680) {
        conv_item(q - 22016, Whhf, Whhf, 200, 50, 200, 208, Whc);
    } else if (q < 25344) {
        conv_item(q - 23680, Whhb, Whhb, 200, 50, 200, 208, Whc + WHC_DIR);
    }
}

// ---------------------------------------------------------------------------
// Split-bf16 MFMA GEMM (round-3 verified version). BM=64 rows, BN padded
// cols, 256 thr = 4 waves column-split. Conflict-free LDS: A [h][kq][64][8],
// B [h][kq][BN][8] (pre-converted, async-staged). 3 mfma terms.
// ---------------------------------------------------------------------------
template<int BN, int KCH, int KREAL, int NCOLS, bool GATHER>
__global__ __launch_bounds__(256)
void gemm_split(const float* __restrict__ A, const int* __restrict__ ids,
                const unsigned short* __restrict__ Bc,
                const float* __restrict__ bias1, const float* __restrict__ bias2,
                int split, float* __restrict__ C) {
    constexpr int NTW = BN / 64;   // 16-col tiles per wave
    __shared__ __align__(16) unsigned short As[2 * 4 * 64 * 8];  // 8 KB
    __shared__ __align__(16) unsigned short Bt[64 * BN];

    const int tid = threadIdx.x;
    const int m0 = blockIdx.x * 64;
    const int w = tid >> 6, lane = tid & 63;
    const int r16 = lane & 15, quad = lane >> 4;
    const int wn = w * (BN / 4);

    const int mA = tid & 63, kqA = tid >> 6;
    const float* arow = GATHER ? (A + (size_t)ids[m0 + mA] * KREAL)
                               : (A + (size_t)(m0 + mA) * KREAL);

    float ar[8];
    {
        int k0 = kqA * 8;
        if (k0 + 8 <= KREAL) {
            float4 p = *(const float4*)(arow + k0);
            float4 q = *(const float4*)(arow + k0 + 4);
            ar[0]=p.x; ar[1]=p.y; ar[2]=p.z; ar[3]=p.w;
            ar[4]=q.x; ar[5]=q.y; ar[6]=q.z; ar[7]=q.w;
        } else {
            #pragma unroll
            for (int e = 0; e < 8; ++e) ar[e] = (k0 + e < KREAL) ? arow[k0 + e] : 0.0f;
        }
    }

    f32x4 acc[4][NTW] = {};

    for (int c = 0; c < KCH; ++c) {
        __syncthreads();
        {
            const unsigned short* src = Bc + (size_t)c * 64 * BN + tid * 8;
            #pragma unroll
            for (int i = 0; i < BN / 32; ++i)
                async_lds16(src + (size_t)i * 2048, Bt + i * 2048 + tid * 8);
        }
        {
            unsigned short h[8], l[8];
            #pragma unroll
            for (int e = 0; e < 8; ++e) split2(ar[e], h[e], l[e]);
            *(bf16x8*)&As[((0 * 4 + kqA) * 64 + mA) * 8] = pack8(h);
            *(bf16x8*)&As[((1 * 4 + kqA) * 64 + mA) * 8] = pack8(l);
        }
        __syncthreads();
        if (c + 1 < KCH) {
            int k0 = (c + 1) * 32 + kqA * 8;
            if (k0 + 8 <= KREAL) {
                float4 p = *(const float4*)(arow + k0);
                float4 q = *(const float4*)(arow + k0 + 4);
                ar[0]=p.x; ar[1]=p.y; ar[2]=p.z; ar[3]=p.w;
                ar[4]=q.x; ar[5]=q.y; ar[6]=q.z; ar[7]=q.w;
            } else {
                #pragma unroll
                for (int e = 0; e < 8; ++e) ar[e] = (k0 + e < KREAL) ? arow[k0 + e] : 0.0f;
            }
        }
        bf16x8 af[2][4];
        #pragma unroll
        for (int i = 0; i < 4; ++i) {
            af[0][i] = *(const bf16x8*)&As[((0 * 4 + quad) * 64 + i * 16 + r16) * 8];
            af[1][i] = *(const bf16x8*)&As[((1 * 4 + quad) * 64 + i * 16 + r16) * 8];
        }
        #pragma unroll
        for (int t = 0; t < NTW; ++t) {
            bf16x8 bh = *(const bf16x8*)&Bt[((0 * 4 + quad) * BN + wn + t * 16 + r16) * 8];
            bf16x8 bl = *(const bf16x8*)&Bt[((1 * 4 + quad) * BN + wn + t * 16 + r16) * 8];
            #pragma unroll
            for (int i = 0; i < 4; ++i) {
                acc[i][t] = __builtin_amdgcn_mfma_f32_16x16x32_bf16(af[0][i], bh, acc[i][t], 0, 0, 0);
                acc[i][t] = __builtin_amdgcn_mfma_f32_16x16x32_bf16(af[1][i], bh, acc[i][t], 0, 0, 0);
                acc[i][t] = __builtin_amdgcn_mfma_f32_16x16x32_bf16(af[0][i], bl, acc[i][t], 0, 0, 0);
            }
        }
    }

    #pragma unroll
    for (int t = 0; t < NTW; ++t) {
        int ncol = wn + t * 16 + r16;
        if (ncol < NCOLS) {
            float bv = (ncol < split) ? bias1[ncol] : bias2[ncol - split];
            #pragma unroll
            for (int i = 0; i < 4; ++i)
                #pragma unroll
                for (int r = 0; r < 4; ++r) {
                    int mrow = m0 + i * 16 + quad * 4 + r;
                    C[(size_t)mrow * NCOLS + ncol] = acc[i][t][r] + bv;
                }
        }
    }
}

// ---------------------------------------------------------------------------
// K2: MFMA-batched BiLSTM, 8 sentences/block, 256 blocks (round-7 verified).
// Counted-vmcnt sync: per step each wave issues exactly 2 DMA + 2 store
// instrs in pinned order; vmcnt(8) at barrier #1 waits exactly for L_t.
// ---------------------------------------------------------------------------
__global__ __launch_bounds__(256)
void lstm_mfma(const float* __restrict__ xg, const unsigned short* __restrict__ Whc,
               float* __restrict__ x) {
    const int bi = blockIdx.x;
    const int dir = bi & 1;
    const int b0 = (bi >> 1) * 8;
    const int tid = threadIdx.x;
    const int w = tid >> 6, lane = tid & 63;
    const int r16 = lane & 15, quad = lane >> 4;

    __shared__ __align__(16) unsigned short Ah[8 * 16 * 8];  // [kq][row16][8]
    __shared__ __align__(16) unsigned short Al[8 * 16 * 8];
    __shared__ __align__(16) float G[208 * 20];              // [gate][row pad20]
    __shared__ __align__(16) float Xs[3][8][268];            // xg ring (lead 2)

    const int n0 = (w == 0) ? 0 : (w == 1) ? 4 : (w == 2) ? 7 : 10;
    const int nc = (w == 0) ? 4 : 3;

    const unsigned short* Wd = Whc + (size_t)dir * WHC_DIR;
    bf16x8 bfr[4][2][2];   // [tile][chunk][hi/lo]
    #pragma unroll
    for (int t = 0; t < 4; ++t) {
        int col = (n0 + ((t < nc) ? t : 0)) * 16 + r16;
        #pragma unroll
        for (int c = 0; c < 2; ++c)
            #pragma unroll
            for (int h = 0; h < 2; ++h)
                bfr[t][c][h] = *(const bf16x8*)&Wd[((((size_t)c * 2 + h) * 4 + quad) * 208 + col) * 8];
    }

    for (int q = tid; q < 512; q += 256) {
        ((unsigned*)Ah)[q] = 0u;   // rows 8..15 stay zero forever
        ((unsigned*)Al)[q] = 0u;
    }

    int ss[2], ms[2];
    bool act[2];
    #pragma unroll
    for (int j = 0; j < 2; ++j) {
        int q = w * 100 + lane + 64 * j;
        ss[j] = q & 7;
        ms[j] = q >> 3;
        act[j] = (lane + 64 * j) < 100;
    }
    float c_reg[2] = {0.0f, 0.0f};

    #pragma unroll
    for (int p = 0; p < 2; ++p) {
        int idx0 = dir ? (63 - p) : p;
        #pragma unroll
        for (int i = 0; i < 2; ++i) {
            int s = w * 2 + i;
            const float* src = xg + ((size_t)(b0 + s) * 64 + idx0) * 400 + dir * 200 + lane * 4;
            async_lds16(src, &Xs[p][s][lane * 4]);
        }
    }
    __syncthreads();

    for (int step = 0; step < 64; ++step) {
        const int buf = step % 3;
        const int idx = dir ? (63 - step) : step;
        {
            int stepn = step + 2; if (stepn > 63) stepn = 63;
            const int slot = (step + 2) % 3;
            const int idxn = dir ? (63 - stepn) : stepn;
            #pragma unroll
            for (int i = 0; i < 2; ++i) {
                int s = w * 2 + i;
                const float* src = xg + ((size_t)(b0 + s) * 64 + idxn) * 400 + dir * 200 + lane * 4;
                async_lds16(src, &Xs[slot][s][lane * 4]);
            }
            __builtin_amdgcn_sched_barrier(0);
        }
        bf16x8 ah[2], al[2];
        #pragma unroll
        for (int c = 0; c < 2; ++c) {
            ah[c] = *(const bf16x8*)&Ah[((c * 4 + quad) * 16 + r16) * 8];
            al[c] = *(const bf16x8*)&Al[((c * 4 + quad) * 16 + r16) * 8];
        }
        f32x4 acc[4] = {};
        #pragma unroll
        for (int t = 0; t < 4; ++t) {
            if (t < nc) {
                #pragma unroll
                for (int c = 0; c < 2; ++c) {
                    acc[t] = __builtin_amdgcn_mfma_f32_16x16x32_bf16(ah[c], bfr[t][c][0], acc[t], 0, 0, 0);
                    acc[t] = __builtin_amdgcn_mfma_f32_16x16x32_bf16(al[c], bfr[t][c][0], acc[t], 0, 0, 0);
                    acc[t] = __builtin_amdgcn_mfma_f32_16x16x32_bf16(ah[c], bfr[t][c][1], acc[t], 0, 0, 0);
                }
            }
        }
        #pragma unroll
        for (int t = 0; t < 4; ++t) {
            if (t < nc) {
                int col = (n0 + t) * 16 + r16;
                *(f32x4*)&G[col * 20 + quad * 4] = acc[t];
            }
        }
        asm volatile("s_waitcnt lgkmcnt(0) vmcnt(8)" ::: "memory");
        __builtin_amdgcn_sched_barrier(0);
        __builtin_amdgcn_s_barrier();
        __builtin_amdgcn_sched_barrier(0);
        #pragma unroll
        for (int j = 0; j < 2; ++j) {
            if (act[j]) {
                int s = ss[j], m = ms[j];
                float gi = G[m * 20 + s]         + Xs[buf][s][m];
                float gf = G[(m + 50) * 20 + s]  + Xs[buf][s][m + 50];
                float gg = G[(m + 100) * 20 + s] + Xs[buf][s][m + 100];
                float go = G[(m + 150) * 20 + s] + Xs[buf][s][m + 150];
                c_reg[j] = fsig2(gf) * c_reg[j] + fsig2(gi) * ftanh2(gg);
                float h = fsig2(go) * ftanh2(c_reg[j]);
                unsigned short hh, hl;
                split2(h, hh, hl);
                Ah[(m >> 3) * 128 + s * 8 + (m & 7)] = hh;
                Al[(m >> 3) * 128 + s * 8 + (m & 7)] = hl;
                x[((size_t)(b0 + s) * 64 + idx) * 100 + dir * 50 + m] = h;
            }
        }
        asm volatile("s_waitcnt lgkmcnt(0)" ::: "memory");
        __builtin_amdgcn_sched_barrier(0);
        __builtin_amdgcn_s_barrier();
        __builtin_amdgcn_sched_barrier(0);
    }
}

// ---------------------------------------------------------------------------
// K4: ChildSum TreeLSTM + pool + classifier, round-10 "wave-tree".
// Diagnosis across r7/r8/r9: per-block parallelism is tiny (level sizes
// 1,32,16,8,4,2,1) and the critical path is 7 dependent levels x (C2
// latency + barriers) at 2 waves/SIMD.  Fix: ONE SENTENCE PER WAVE,
// BARRIER-FREE.  256 blocks x 4 waves; wave w owns sentence bid*4+w; all
// node dependencies are wave-internal (lockstep + compiler lgkmcnt) -- the
// only s_barrier is after weight staging.  Per node (lane m owns element
// m): fused msg (3 Us rows/lane) -> gates -> pool accum in REGISTER ->
// HV write -> F matvec -> scatter into own HS/FC (lane-owned, no atomics).
// C2 reads coalesced (lane m -> base+m) and prefetched one node ahead.
// LDS: Us 31.2K + Fs 10.4K + HS/FC 53.2K + HV/TMS 2K = 97.5 KB ->
// 1 block/CU, grid 256 = exactly one block per CU.
// ---------------------------------------------------------------------------
__global__ __launch_bounds__(256)
void tree_kernel(const float* __restrict__ C2,
                 const float* __restrict__ Uw, const float* __restrict__ Ub,
                 const float* __restrict__ Fw, const float* __restrict__ Fb,
                 const float* __restrict__ tmask,
                 const float* __restrict__ Cw, const float* __restrict__ Cb,
                 float* __restrict__ out) {
    const int tid = threadIdx.x;
    const int w = tid >> 6, lane = tid & 63;
    const int s = blockIdx.x * 4 + w;          // sentence for this wave

    __shared__ __align__(16) float Us[150][52];    // U_iou_w rows
    __shared__ __align__(16) float Fs[50][52];     // U_f_w rows
    __shared__ __align__(16) float HS[4][32][52];  // per-wave h_sum
    __shared__ __align__(16) float FC[4][32][52];  // per-wave fc_sum
    __shared__ __align__(16) float HV[4][64];      // per-wave current-node h
    __shared__ __align__(16) float TMS[4][64];     // per-wave target mask

    for (int q = tid; q < 7500; q += 256) Us[q / 50][q % 50] = Uw[q];
    for (int q = tid; q < 2500; q += 256) Fs[q / 50][q % 50] = Fw[q];
    for (int q = tid; q < 4 * 32 * 52; q += 256) {
        int ww = q / (32 * 52), r = q - ww * (32 * 52);
        HS[ww][r / 52][r % 52] = 0.0f;
        FC[ww][r / 52][r % 52] = 0.0f;
    }
    TMS[w][lane] = tmask[(size_t)s * 64 + lane];
    __syncthreads();   // the ONLY barrier; waves run independently after this

    const bool act = lane < 50;
    const int m = act ? lane : 49;             // clamped; stores guarded by act
    const float ub0 = Ub[m], ub1 = Ub[50 + m], ub2 = Ub[100 + m];
    const float fb = Fb[m];
    const float* c2s = C2 + (size_t)s * 64 * 200;

    float pr = 0.0f;                           // pool[m] accumulator (register)
    float pc0, pc1, pc2, pc3;
    {
        const float* nb = c2s + 63 * 200;      // first node processed is 63
        pc0 = nb[m]; pc1 = nb[50 + m]; pc2 = nb[100 + m]; pc3 = nb[150 + m];
    }

    for (int l = 6; l >= 0; --l) {
        const int lo = (1 << l) - 1;
        const int hi = min((1 << (l + 1)) - 2, 63);
        for (int loc = lo; loc <= hi; ++loc) {
            // prefetch next node's C2 row (coalesced: lane m -> base+m)
            const int nxt = (loc < hi) ? (loc + 1) : ((l > 0) ? ((1 << (l - 1)) - 1) : loc);
            float nc0, nc1, nc2, nc3;
            {
                const float* nb = c2s + (size_t)nxt * 200;
                nc0 = nb[m]; nc1 = nb[50 + m]; nc2 = nb[100 + m]; nc3 = nb[150 + m];
            }
            const bool hasch = (loc <= 31);    // children 2*loc+1 <= 63
            float mi = 0.0f, mo = 0.0f, mu = 0.0f, fcv = 0.0f;
            if (hasch) {
                const float* hs = &HS[w][loc][0];
                const float* u0 = &Us[m][0];
                const float* u1 = &Us[50 + m][0];
                const float* u2 = &Us[100 + m][0];
                float i0=0,i1=0,i2=0,i3=0, o0=0,o1=0,o2=0,o3=0, g0=0,g1=0,g2=0,g3=0;
                #pragma unroll
                for (int j = 0; j < 12; ++j) {
                    float4 h4 = *(const float4*)&hs[j * 4];   // broadcast
                    float4 a4 = *(const float4*)&u0[j * 4];
                    float4 b4 = *(const float4*)&u1[j * 4];
                    float4 c4 = *(const float4*)&u2[j * 4];
                    i0 += a4.x*h4.x; i1 += a4.y*h4.y; i2 += a4.z*h4.z; i3 += a4.w*h4.w;
                    o0 += b4.x*h4.x; o1 += b4.y*h4.y; o2 += b4.z*h4.z; o3 += b4.w*h4.w;
                    g0 += c4.x*h4.x; g1 += c4.y*h4.y; g2 += c4.z*h4.z; g3 += c4.w*h4.w;
                }
                float h48 = hs[48], h49 = hs[49];
                mi = ub0 + (i0 + i1) + (i2 + i3) + u0[48]*h48 + u0[49]*h49;
                mo = ub1 + (o0 + o1) + (o2 + o3) + u1[48]*h48 + u1[49]*h49;
                mu = ub2 + (g0 + g1) + (g2 + g3) + u2[48]*h48 + u2[49]*h49;
                fcv = FC[w][loc][m];
            }
            float ig = pc0 + mi, og = pc1 + mo, ug = pc2 + mu;
            float cn = fsig2(ig) * ftanh2(ug) + fcv;
            float hn = pc3 + fsig2(og) * ftanh2(cn);
            pr += TMS[w][loc] * hn;            // broadcast read; tv=0 for non-targets
            if (act) HV[w][lane] = hn;
            {
                const float* hv = &HV[w][0];
                const float* f0 = &Fs[m][0];
                float a0 = 0, a1 = 0, a2 = 0, a3 = 0;
                #pragma unroll
                for (int j = 0; j < 12; ++j) {
                    float4 h4 = *(const float4*)&hv[j * 4];   // broadcast
                    float4 f4 = *(const float4*)&f0[j * 4];
                    a0 += f4.x*h4.x; a1 += f4.y*h4.y; a2 += f4.z*h4.z; a3 += f4.w*h4.w;
                }
                float facc = fb + (a0 + a1) + (a2 + a3) + f0[48]*hv[48] + f0[49]*hv[49];
                if (act && loc > 0) {
                    int p = (loc - 1) >> 1;
                    float fm = fsig2(facc) * cn;
                    HS[w][p][lane] += hn;      // lane-owned element: no atomics
                    FC[w][p][lane] += fm;
                }
            }
            pc0 = nc0; pc1 = nc1; pc2 = nc2; pc3 = nc3;
        }
    }

    // ---- masked mean pool ----
    float ws = 0.0f;
    #pragma unroll
    for (int j = 0; j < 16; ++j) {
        float4 t4 = *(const float4*)&TMS[w][j * 4];
        ws += (t4.x + t4.y) + (t4.z + t4.w);
    }
    float p = pr / ws;
    if (act) {
        out[3072 + (size_t)s * 50 + lane] = p;
        HV[w][lane] = p;                       // stage pool for classifier
    }
    // ---- classifier (3 lanes per wave) ----
    if (lane < 3) {
        float acc = Cb[lane];
        const float* crow = Cw + lane * 50;
        for (int k = 0; k < 50; ++k) acc += crow[k] * HV[w][k];
        out[(size_t)s * 3 + lane] = acc;
    }
}

// ---------------------------------------------------------------------------
extern "C" void kernel_launch(void* const* d_in, const int* in_sizes, int n_in,
                              void* d_out, int out_size, void* d_ws, size_t ws_size,
                              hipStream_t stream) {
    (void)in_sizes; (void)n_in; (void)out_size; (void)ws_size;
    const int*   ids   = (const int*)d_in[0];
    const float* tmask = (const float*)d_in[3];
    const float* table = (const float*)d_in[5];
    const float* Wihf  = (const float*)d_in[6];
    const float* Whhf  = (const float*)d_in[7];
    const float* bf    = (const float*)d_in[8];
    const float* Wihb  = (const float*)d_in[9];
    const float* Whhb  = (const float*)d_in[10];
    const float* bb    = (const float*)d_in[11];
    const float* Wiou  = (const float*)d_in[12];
    const float* Uiouw = (const float*)d_in[13];
    const float* Uioub = (const float*)d_in[14];
    const float* biou  = (const float*)d_in[15];
    const float* Ufw   = (const float*)d_in[16];
    const float* Ufb   = (const float*)d_in[17];
    const float* Hw    = (const float*)d_in[18];
    const float* Hb    = (const float*)d_in[19];
    const float* Cw    = (const float*)d_in[20];
    const float* Cb    = (const float*)d_in[21];
    float* out = (float*)d_out;

    float* wsf = (float*)d_ws;
    float* xg = wsf;                                  // 65536*400 f32 (C2 later)
    float* x  = wsf + (size_t)65536 * 400;            // 65536*100 f32
    float* C2 = wsf;
    unsigned short* B1c = (unsigned short*)(wsf + 32768000);  // 10*2*4*448*8 ush
    unsigned short* B3c = (unsigned short*)(wsf + 32911360);  // 4*2*4*256*8 ush
    unsigned short* Whc = (unsigned short*)(wsf + 32944128);  // 2 * WHC_DIR ush

    // K0: all weight pre-conversions in ONE launch (25344 items)
    conv_fused<<<99, 256, 0, stream>>>(Wihf, Wihb, Wiou, Hw, Whhf, Whhb,
                                       B1c, B3c, Whc);
    // K1: xg = gather(embed)@[W_ih_f;W_ih_b]^T + bias   (N x 400)
    gemm_split<448, 10, 300, 400, true><<<1024, 256, 0, stream>>>(
        table, ids, B1c, bf, bb, 200, xg);
    // K2: MFMA BiLSTM -> x (N x 100) = [hf | hb]   (8 sents/block, 256 blocks)
    lstm_mfma<<<256, 256, 0, stream>>>(xg, Whc, x);
    // K3: C2 = x@[W_iou^T | H_w^T] + [b_iou | H_b]   (N x 200)
    gemm_split<256, 4, 100, 200, false><<<1024, 256, 0, stream>>>(
        x, nullptr, B3c, biou, Hb, 150, C2);
    // K4: TreeLSTM + pool + classifier (wave-per-sentence, barrier-free)
    tree_kernel<<<256, 256, 0, stream>>>(
        C2, Uiouw, Uioub, Ufw, Ufb, tmask, Cw, Cb, out);
}